// Round 4
// baseline (6747.638 us; speedup 1.0000x reference)
//
#include <hip/hip_runtime.h>
#include <stdint.h>

// Problem constants
#define B_ 32
#define T_ 2048
#define D_ 512
#define N_ 512
#define NG 2048   // 4 gates * N

typedef _Float16 f16;
typedef _Float16 half2v __attribute__((ext_vector_type(2)));
typedef _Float16 half8  __attribute__((ext_vector_type(8)));
typedef float    float4v __attribute__((ext_vector_type(4)));
typedef unsigned long long u64;

union U32H2 { unsigned u; half2v h; };

static __device__ __forceinline__ float fdot2(unsigned a, unsigned b, float c) {
#if __has_builtin(__builtin_amdgcn_fdot2)
    U32H2 ua; ua.u = a; U32H2 ub; ub.u = b;
    return __builtin_amdgcn_fdot2(ua.h, ub.h, c, false);
#else
    U32H2 ua; ua.u = a; U32H2 ub; ub.u = b;
    c += (float)ua.h[0] * (float)ub.h[0];
    c += (float)ua.h[1] * (float)ub.h[1];
    return c;
#endif
}

// sc0 load: bypass L1, read the XCD's (shared) L2. Own waitcnt so result is usable.
static __device__ __forceinline__ u64 load_b64_sc0(const u64* p) {
    u64 v;
    asm volatile("global_load_dwordx2 %0, %1, off sc0\n\ts_waitcnt vmcnt(0)"
                 : "=v"(v) : "v"(p) : "memory");
    return v;
}
// plain store: write-through to the local XCD L2 (fast path for same-XCD peers)
static __device__ __forceinline__ void store_b64_plain(u64* p, u64 v) {
    asm volatile("global_store_dwordx2 %0, %1, off" :: "v"(p), "v"(v) : "memory");
}

static __device__ __forceinline__ float sigmoid_fast(float x) {
    return 1.f / (1.f + __expf(-x));
}
static __device__ __forceinline__ float tanh_fast(float x) {
    x = fminf(fmaxf(x, -15.f), 15.f);   // tanh saturates to +-1 well before 15
    float e = __expf(2.f * x);
    return (e - 1.f) / (e + 1.f);
}

// ---------------- prep: cast x (f32) -> f16 ----------------
__global__ void prep_cast(const float* __restrict__ x, f16* __restrict__ x16) {
    long i = ((long)blockIdx.x * 256 + threadIdx.x) * 4;
    float4 v = *(const float4*)(x + i);
    union { f16 h[4]; uint2 u; } pk;
    pk.h[0] = (f16)v.x; pk.h[1] = (f16)v.y; pk.h[2] = (f16)v.z; pk.h[3] = (f16)v.w;
    *(uint2*)(x16 + i) = pk.u;
}

// ---------------- prep: transpose+cast weights, biases ----------------
__global__ void prep_w(const float* __restrict__ Wi, const float* __restrict__ Ui,
                       const float* __restrict__ Wf, const float* __restrict__ Uf,
                       const float* __restrict__ Wg, const float* __restrict__ Ug,
                       const float* __restrict__ Wc, const float* __restrict__ Uc,
                       const float* __restrict__ Wo,
                       const float* __restrict__ bi, const float* __restrict__ bff,
                       const float* __restrict__ bg, const float* __restrict__ bc,
                       f16* __restrict__ wt, f16* __restrict__ ut,
                       f16* __restrict__ wot, float* __restrict__ bias)
{
    const int y = blockIdx.y;
    const int e = blockIdx.x * 256 + threadIdx.x;   // 0..262143
    if (y < 4) {
        const float* src = (y == 0) ? Wi : (y == 1) ? Wf : (y == 2) ? Wg : Wc;
        int col = e >> 9, d = e & 511;
        wt[(long)y * 512 * 512 + e] = (f16)src[(long)d * 512 + col];   // wt[(g*512+col)][d]
    } else if (y < 8) {
        const float* src = (y == 4) ? Ui : (y == 5) ? Uf : (y == 6) ? Ug : Uc;
        int col = e >> 9, d = e & 511;
        ut[(long)(y - 4) * 512 * 512 + e] = (f16)src[(long)d * 512 + col];
    } else if (y == 8) {
        int col = e >> 9, d = e & 511;
        wot[e] = (f16)Wo[(long)d * 512 + col];
    } else {
        if (e < 2048) {
            const float* bsrc = (e < 512) ? bi : (e < 1024) ? bff : (e < 1536) ? bg : bc;
            bias[e] = bsrc[e & 511];
        }
    }
}

// ---------------- phase 1: xpre[b][t][2048] = x @ [Wi|Wf|Wg|Wc] + bias (f16 out) ----------------
__launch_bounds__(256)
__global__ void gemm_xw(const f16* __restrict__ A, const f16* __restrict__ Bt,
                        const float* __restrict__ bias, f16* __restrict__ C)
{
    __shared__ f16 sA[128 * 32];
    __shared__ f16 sB[128 * 32];
    const int tid = threadIdx.x;
    const int m0 = blockIdx.y * 128;
    const int n0 = blockIdx.x * 128;
    const int wave = tid >> 6, lane = tid & 63;
    const int wm = wave >> 1, wn = wave & 1;
    const int lrow = lane & 15, quad = lane >> 4;

    float4v acc[4][4];
#pragma unroll
    for (int i = 0; i < 4; i++)
#pragma unroll
        for (int j = 0; j < 4; j++) acc[i][j] = (float4v){0.f, 0.f, 0.f, 0.f};

    const int srow = tid >> 2;        // 0..63
    const int sk8 = (tid & 3) * 8;    // 0,8,16,24

    for (int k0 = 0; k0 < 512; k0 += 32) {
#pragma unroll
        for (int rr = 0; rr < 128; rr += 64) {
            const int row = rr + srow;
            *(uint4*)&sA[row * 32 + sk8] = *(const uint4*)&A[(long)(m0 + row) * 512 + k0 + sk8];
            *(uint4*)&sB[row * 32 + sk8] = *(const uint4*)&Bt[(long)(n0 + row) * 512 + k0 + sk8];
        }
        __syncthreads();
        half8 af[4], bf[4];
#pragma unroll
        for (int mi = 0; mi < 4; mi++)
            af[mi] = *(half8*)&sA[(wm * 64 + mi * 16 + lrow) * 32 + quad * 8];
#pragma unroll
        for (int ni = 0; ni < 4; ni++)
            bf[ni] = *(half8*)&sB[(wn * 64 + ni * 16 + lrow) * 32 + quad * 8];
#pragma unroll
        for (int mi = 0; mi < 4; mi++)
#pragma unroll
            for (int ni = 0; ni < 4; ni++)
                acc[mi][ni] = __builtin_amdgcn_mfma_f32_16x16x32_f16(af[mi], bf[ni], acc[mi][ni], 0, 0, 0);
        __syncthreads();
    }
#pragma unroll
    for (int mi = 0; mi < 4; mi++)
#pragma unroll
        for (int ni = 0; ni < 4; ni++)
#pragma unroll
            for (int r = 0; r < 4; r++) {
                int m = m0 + wm * 64 + mi * 16 + quad * 4 + r;
                int n = n0 + wn * 64 + ni * 16 + lrow;
                C[(long)m * NG + n] = (f16)(acc[mi][ni][r] + bias[n]);
            }
}

// ---------------- phase 3: out[b][t][n] = relu(hs @ Wo + bo) (f32 out, row remap) ----------------
__launch_bounds__(256)
__global__ void gemm_hw(const f16* __restrict__ A, const f16* __restrict__ Bt,
                        const float* __restrict__ bias, float* __restrict__ out)
{
    __shared__ f16 sA[128 * 32];
    __shared__ f16 sB[128 * 32];
    const int tid = threadIdx.x;
    const int m0 = blockIdx.y * 128;
    const int n0 = blockIdx.x * 128;
    const int wave = tid >> 6, lane = tid & 63;
    const int wm = wave >> 1, wn = wave & 1;
    const int lrow = lane & 15, quad = lane >> 4;

    float4v acc[4][4];
#pragma unroll
    for (int i = 0; i < 4; i++)
#pragma unroll
        for (int j = 0; j < 4; j++) acc[i][j] = (float4v){0.f, 0.f, 0.f, 0.f};

    const int srow = tid >> 2;
    const int sk8 = (tid & 3) * 8;

    for (int k0 = 0; k0 < 512; k0 += 32) {
#pragma unroll
        for (int rr = 0; rr < 128; rr += 64) {
            const int row = rr + srow;
            *(uint4*)&sA[row * 32 + sk8] = *(const uint4*)&A[(long)(m0 + row) * 512 + k0 + sk8];
            *(uint4*)&sB[row * 32 + sk8] = *(const uint4*)&Bt[(long)(n0 + row) * 512 + k0 + sk8];
        }
        __syncthreads();
        half8 af[4], bf[4];
#pragma unroll
        for (int mi = 0; mi < 4; mi++)
            af[mi] = *(half8*)&sA[(wm * 64 + mi * 16 + lrow) * 32 + quad * 8];
#pragma unroll
        for (int ni = 0; ni < 4; ni++)
            bf[ni] = *(half8*)&sB[(wn * 64 + ni * 16 + lrow) * 32 + quad * 8];
#pragma unroll
        for (int mi = 0; mi < 4; mi++)
#pragma unroll
            for (int ni = 0; ni < 4; ni++)
                acc[mi][ni] = __builtin_amdgcn_mfma_f32_16x16x32_f16(af[mi], bf[ni], acc[mi][ni], 0, 0, 0);
        __syncthreads();
    }
#pragma unroll
    for (int mi = 0; mi < 4; mi++)
#pragma unroll
        for (int ni = 0; ni < 4; ni++)
#pragma unroll
            for (int r = 0; r < 4; r++) {
                int m = m0 + wm * 64 + mi * 16 + quad * 4 + r;   // m = t*B + b
                int n = n0 + wn * 64 + ni * 16 + lrow;
                float v = acc[mi][ni][r] + bias[n];
                v = fmaxf(v, 0.f);
                int t = m >> 5, b = m & 31;
                out[(long)b * (T_ * (long)N_) + (long)t * N_ + n] = v;
            }
}

// ---------------- phase 2: the recurrence ----------------
// 32 groups (batch) x 8 slice-blocks x 512 threads. Lane map: within wave w,
// lane = g*16 + eoff*2 + hh covers gate g, element e=w*8+eoff, row-half hh of
// column gcol=g*512+s*64+w*8+eoff. All reduce/gate/pack work is wave-local
// shuffles -> ONE barrier per step. h exchange: fast slot (plain store ->
// same-XCD L2, sc0 poll) + sc1/LLC fallback slot checked every 8th miss
// (correct under any block->XCD mapping). Tag travels with data in one u64.
__launch_bounds__(512, 2)
__global__ void lstm_rec(const f16* __restrict__ Ut,      // [2048 cols][512 rows] f16
                         const f16* __restrict__ xpre,    // [B][T][2048] f16
                         u64* __restrict__ hgF,           // [2][32][256] fast tagged h pairs
                         u64* __restrict__ hgS,           // [2][32][256] slow (LLC) tagged h pairs
                         unsigned* __restrict__ hs32)     // [T][B][256] u32 (packed f16x2)
{
    const int tid = threadIdx.x;
    const int bb = blockIdx.x & 31;   // batch
    const int s  = blockIdx.x >> 5;   // slice 0..7 (blockIdx = s*32+bb; all == bb mod 8 -> same XCD)
    const int w  = tid >> 6;          // wave 0..7
    const int l  = tid & 63;
    const int g    = l >> 4;          // gate 0..3
    const int eoff = (l >> 1) & 7;    // element within wave's 8
    const int hh   = l & 1;           // row-half
    const int gcol = g * 512 + s * 64 + w * 8 + eoff;   // global gate-column

    // padded double-buffered h (parity): even half words 0..127, odd half words 132..259
    __shared__ __align__(16) unsigned hbuf[2][264];

    // U half-column in registers (statically indexed)
    uint4 u[32];
    const uint4* Ub = (const uint4*)(Ut + (long)gcol * 512) + hh * 32;
#pragma unroll
    for (int k = 0; k < 32; k++) u[k] = Ub[k];

    if (tid < 264) hbuf[0][tid] = 0u;   // h_{-1} = 0
    float cst = 0.f;                    // c-state for element w*8+eoff (redundant across g,hh)

    const f16* xp_base = xpre + (long)bb * T_ * NG + gcol;
    // prologue prefetch of xpre[0]
    float xpv = (hh == 0) ? (float)xp_base[0] : 0.f;

    const int pollskip = (tid >> 5) == s;   // own-slice words arrive via LDS directly
    const size_t exbase = (size_t)bb * 256;

    for (int t = 0; t < T_; ++t) {
        // ---- acquire h_{t-1}: poll fast slot (XCD L2), fallback to LLC slot ----
        if (t > 0 && tid < 256 && !pollskip) {
            const size_t off = (size_t)(t & 1) * 8192 + exbase + tid;
            const u64* fs = hgF + off;
            const u64* ss = hgS + off;
            const unsigned tag = (unsigned)t;
            u64 v; unsigned miss = 0;
            for (;;) {
                v = load_b64_sc0(fs);
                if ((unsigned)(v >> 32) == tag) break;
                if ((++miss & 7u) == 0u) {
                    v = __hip_atomic_load(ss, __ATOMIC_RELAXED, __HIP_MEMORY_SCOPE_AGENT);
                    if ((unsigned)(v >> 32) == tag) break;
                }
            }
            int j = tid;
            hbuf[t & 1][j + ((j >> 7) << 2)] = (unsigned)v;   // +4 pad for j>=128
        }
        __syncthreads();

        // prefetch next step's xpre AFTER the poll (keeps poll's vmcnt clean)
        float xpv_next = 0.f;
        if (hh == 0) {
            int tn = (t + 1 < T_) ? t + 1 : t;
            xpv_next = (float)xp_base[(long)tn * NG];
        }

        // ---- dot over this half-column (conflict-free padded broadcast reads) ----
        const unsigned* bufR = hbuf[t & 1];
        const uint4* hb = ((const uint4*)bufR) + (hh ? 33 : 0);
        float a0 = 0.f, a1 = 0.f, a2 = 0.f, a3 = 0.f;
#pragma unroll
        for (int k = 0; k < 32; k++) {
            uint4 hv = hb[k];
            a0 = fdot2(hv.x, u[k].x, a0);
            a1 = fdot2(hv.y, u[k].y, a1);
            a2 = fdot2(hv.z, u[k].z, a2);
            a3 = fdot2(hv.w, u[k].w, a3);
        }
        float sum = (a0 + a1) + (a2 + a3);
        if (hh == 0) sum += xpv;
        float tot = sum + __shfl_xor(sum, 1);      // both halves -> full preactivation

        // gather the 4 gate preactivations for my element (wave-local shuffles)
        const int base = l & 15;
        float pi = __shfl(tot, base);
        float pf = __shfl(tot, base + 16);
        float pg = __shfl(tot, base + 32);
        float pc = __shfl(tot, base + 48);

        float gi = sigmoid_fast(pi);
        float gf = sigmoid_fast(pf);
        float gg = sigmoid_fast(pg);
        float ct = tanh_fast(pc);
        cst = gf * cst + gi * ct;
        float h = gg * tanh_fast(cst);

        // pack element pairs: even-eoff lanes take neighbor's h
        float ho = __shfl_xor(h, 2);
        if ((l & 3) == 0 && g == 0) {              // lanes 0,4,8,12: eoff even, hh=0, gate 0
            union { f16 hx[2]; unsigned u; } pk;
            pk.hx[0] = (f16)h;  pk.hx[1] = (f16)ho;
            const int j = s * 32 + w * 4 + (l >> 2);          // global h-word index
            const u64 pv = ((u64)(unsigned)(t + 1) << 32) | (u64)pk.u;
            const size_t off = (size_t)((t + 1) & 1) * 8192 + exbase + j;
            store_b64_plain(hgF + off, pv);                    // fast: local XCD L2
            __hip_atomic_store(hgS + off, pv, __ATOMIC_RELAXED, __HIP_MEMORY_SCOPE_AGENT);
            hs32[((long)t * B_ + bb) * 256 + j] = pk.u;        // history for gemm_hw
            hbuf[(t + 1) & 1][j + ((j >> 7) << 2)] = pk.u;     // own slice direct to LDS
        }
        xpv = xpv_next;
        // single barrier per step: next iteration's __syncthreads orders everything
    }
}

// ---------------- launch ----------------
extern "C" void kernel_launch(void* const* d_in, const int* in_sizes, int n_in,
                              void* d_out, int out_size, void* d_ws, size_t ws_size,
                              hipStream_t stream)
{
    const float* x  = (const float*)d_in[0];
    const float* Wi = (const float*)d_in[1];
    const float* Ui = (const float*)d_in[2];
    const float* Wf = (const float*)d_in[3];
    const float* Uf = (const float*)d_in[4];
    const float* Wg = (const float*)d_in[5];
    const float* Ug = (const float*)d_in[6];
    const float* Wc = (const float*)d_in[7];
    const float* Uc = (const float*)d_in[8];
    const float* Wo = (const float*)d_in[9];
    const float* bi = (const float*)d_in[10];
    const float* bf = (const float*)d_in[11];
    const float* bg = (const float*)d_in[12];
    const float* bc = (const float*)d_in[13];
    const float* bo = (const float*)d_in[14];

    char* ws = (char*)d_ws;
    f16*      x16   = (f16*)(ws + 0L);            // 64 MB
    f16*      xpre  = (f16*)(ws + 67108864L);     // 256 MB
    f16*      hs    = (f16*)(ws + 335544320L);    // 64 MB
    f16*      wt    = (f16*)(ws + 402653184L);    // 2 MB
    f16*      ut    = (f16*)(ws + 404750336L);    // 2 MB
    f16*      wot   = (f16*)(ws + 406847488L);    // 0.5 MB
    float*    bias  = (float*)(ws + 407371776L);  // 8 KB
    u64*      hgF   = (u64*)(ws + 407379968L);    // 128 KB fast exchange
    u64*      hgS   = (u64*)(ws + 407511040L);    // 128 KB LLC-fallback exchange
    // both exchange arrays re-poisoned to 0xAA each call -> tag 0xAAAAAAAA never
    // matches a real t in [1,2048], so stale data cannot satisfy a poll.

    prep_cast<<<dim3(32768), dim3(256), 0, stream>>>(x, x16);
    prep_w<<<dim3(1024, 10), dim3(256), 0, stream>>>(Wi, Ui, Wf, Uf, Wg, Ug, Wc, Uc, Wo,
                                                     bi, bf, bg, bc, wt, ut, wot, bias);
    gemm_xw<<<dim3(16, 512), dim3(256), 0, stream>>>(x16, wt, bias, xpre);
    lstm_rec<<<dim3(256), dim3(512), 0, stream>>>(ut, xpre, hgF, hgS, (unsigned*)hs);
    gemm_hw<<<dim3(4, 512), dim3(256), 0, stream>>>(hs, wot, bo, (float*)d_out);
}

// Round 5
// 5624.217 us; speedup vs baseline: 1.1997x; 1.1997x over previous
//
#include <hip/hip_runtime.h>
#include <stdint.h>

// Problem constants
#define B_ 32
#define T_ 2048
#define D_ 512
#define N_ 512
#define NG 2048   // 4 gates * N

typedef _Float16 f16;
typedef _Float16 half2v __attribute__((ext_vector_type(2)));
typedef _Float16 half8  __attribute__((ext_vector_type(8)));
typedef float    float4v __attribute__((ext_vector_type(4)));
typedef unsigned uint4v  __attribute__((ext_vector_type(4)));
typedef unsigned long long u64;

union U32H2 { unsigned u; half2v h; };

static __device__ __forceinline__ float fdot2(unsigned a, unsigned b, float c) {
#if __has_builtin(__builtin_amdgcn_fdot2)
    U32H2 ua; ua.u = a; U32H2 ub; ub.u = b;
    return __builtin_amdgcn_fdot2(ua.h, ub.h, c, false);
#else
    U32H2 ua; ua.u = a; U32H2 ub; ub.u = b;
    c += (float)ua.h[0] * (float)ub.h[0];
    c += (float)ua.h[1] * (float)ub.h[1];
    return c;
#endif
}

// device-scope (sc1) 16B load of two tagged u64 slots; own waitcnt.
static __device__ __forceinline__ uint4v load_2slots_sc1(const u64* p) {
    uint4v v;
    asm volatile("global_load_dwordx4 %0, %1, off sc1\n\ts_waitcnt vmcnt(0)"
                 : "=v"(v) : "v"(p) : "memory");
    return v;
}

static __device__ __forceinline__ float sigmoid_fast(float x) {
    return 1.f / (1.f + __expf(-x));
}
static __device__ __forceinline__ float tanh_fast(float x) {
    x = fminf(fmaxf(x, -15.f), 15.f);   // tanh saturates to +-1 well before 15
    float e = __expf(2.f * x);
    return (e - 1.f) / (e + 1.f);
}

// ---------------- prep: cast x (f32) -> f16 ----------------
__global__ void prep_cast(const float* __restrict__ x, f16* __restrict__ x16) {
    long i = ((long)blockIdx.x * 256 + threadIdx.x) * 4;
    float4 v = *(const float4*)(x + i);
    union { f16 h[4]; uint2 u; } pk;
    pk.h[0] = (f16)v.x; pk.h[1] = (f16)v.y; pk.h[2] = (f16)v.z; pk.h[3] = (f16)v.w;
    *(uint2*)(x16 + i) = pk.u;
}

// ---------------- prep: transpose+cast weights, biases ----------------
__global__ void prep_w(const float* __restrict__ Wi, const float* __restrict__ Ui,
                       const float* __restrict__ Wf, const float* __restrict__ Uf,
                       const float* __restrict__ Wg, const float* __restrict__ Ug,
                       const float* __restrict__ Wc, const float* __restrict__ Uc,
                       const float* __restrict__ Wo,
                       const float* __restrict__ bi, const float* __restrict__ bff,
                       const float* __restrict__ bg, const float* __restrict__ bc,
                       f16* __restrict__ wt, f16* __restrict__ ut,
                       f16* __restrict__ wot, float* __restrict__ bias)
{
    const int y = blockIdx.y;
    const int e = blockIdx.x * 256 + threadIdx.x;   // 0..262143
    if (y < 4) {
        const float* src = (y == 0) ? Wi : (y == 1) ? Wf : (y == 2) ? Wg : Wc;
        int col = e >> 9, d = e & 511;
        wt[(long)y * 512 * 512 + e] = (f16)src[(long)d * 512 + col];   // wt[(g*512+col)][d]
    } else if (y < 8) {
        const float* src = (y == 4) ? Ui : (y == 5) ? Uf : (y == 6) ? Ug : Uc;
        int col = e >> 9, d = e & 511;
        ut[(long)(y - 4) * 512 * 512 + e] = (f16)src[(long)d * 512 + col];
    } else if (y == 8) {
        int col = e >> 9, d = e & 511;
        wot[e] = (f16)Wo[(long)d * 512 + col];
    } else {
        if (e < 2048) {
            const float* bsrc = (e < 512) ? bi : (e < 1024) ? bff : (e < 1536) ? bg : bc;
            bias[e] = bsrc[e & 511];
        }
    }
}

// ---------------- phase 1: xpre[b][t][2048] = x @ [Wi|Wf|Wg|Wc] + bias (f16 out) ----------------
__launch_bounds__(256)
__global__ void gemm_xw(const f16* __restrict__ A, const f16* __restrict__ Bt,
                        const float* __restrict__ bias, f16* __restrict__ C)
{
    __shared__ f16 sA[128 * 32];
    __shared__ f16 sB[128 * 32];
    const int tid = threadIdx.x;
    const int m0 = blockIdx.y * 128;
    const int n0 = blockIdx.x * 128;
    const int wave = tid >> 6, lane = tid & 63;
    const int wm = wave >> 1, wn = wave & 1;
    const int lrow = lane & 15, quad = lane >> 4;

    float4v acc[4][4];
#pragma unroll
    for (int i = 0; i < 4; i++)
#pragma unroll
        for (int j = 0; j < 4; j++) acc[i][j] = (float4v){0.f, 0.f, 0.f, 0.f};

    const int srow = tid >> 2;        // 0..63
    const int sk8 = (tid & 3) * 8;    // 0,8,16,24

    for (int k0 = 0; k0 < 512; k0 += 32) {
#pragma unroll
        for (int rr = 0; rr < 128; rr += 64) {
            const int row = rr + srow;
            *(uint4*)&sA[row * 32 + sk8] = *(const uint4*)&A[(long)(m0 + row) * 512 + k0 + sk8];
            *(uint4*)&sB[row * 32 + sk8] = *(const uint4*)&Bt[(long)(n0 + row) * 512 + k0 + sk8];
        }
        __syncthreads();
        half8 af[4], bf[4];
#pragma unroll
        for (int mi = 0; mi < 4; mi++)
            af[mi] = *(half8*)&sA[(wm * 64 + mi * 16 + lrow) * 32 + quad * 8];
#pragma unroll
        for (int ni = 0; ni < 4; ni++)
            bf[ni] = *(half8*)&sB[(wn * 64 + ni * 16 + lrow) * 32 + quad * 8];
#pragma unroll
        for (int mi = 0; mi < 4; mi++)
#pragma unroll
            for (int ni = 0; ni < 4; ni++)
                acc[mi][ni] = __builtin_amdgcn_mfma_f32_16x16x32_f16(af[mi], bf[ni], acc[mi][ni], 0, 0, 0);
        __syncthreads();
    }
#pragma unroll
    for (int mi = 0; mi < 4; mi++)
#pragma unroll
        for (int ni = 0; ni < 4; ni++)
#pragma unroll
            for (int r = 0; r < 4; r++) {
                int m = m0 + wm * 64 + mi * 16 + quad * 4 + r;
                int n = n0 + wn * 64 + ni * 16 + lrow;
                C[(long)m * NG + n] = (f16)(acc[mi][ni][r] + bias[n]);
            }
}

// ---------------- phase 3: out[b][t][n] = relu(hs @ Wo + bo) (f32 out, row remap) ----------------
__launch_bounds__(256)
__global__ void gemm_hw(const f16* __restrict__ A, const f16* __restrict__ Bt,
                        const float* __restrict__ bias, float* __restrict__ out)
{
    __shared__ f16 sA[128 * 32];
    __shared__ f16 sB[128 * 32];
    const int tid = threadIdx.x;
    const int m0 = blockIdx.y * 128;
    const int n0 = blockIdx.x * 128;
    const int wave = tid >> 6, lane = tid & 63;
    const int wm = wave >> 1, wn = wave & 1;
    const int lrow = lane & 15, quad = lane >> 4;

    float4v acc[4][4];
#pragma unroll
    for (int i = 0; i < 4; i++)
#pragma unroll
        for (int j = 0; j < 4; j++) acc[i][j] = (float4v){0.f, 0.f, 0.f, 0.f};

    const int srow = tid >> 2;
    const int sk8 = (tid & 3) * 8;

    for (int k0 = 0; k0 < 512; k0 += 32) {
#pragma unroll
        for (int rr = 0; rr < 128; rr += 64) {
            const int row = rr + srow;
            *(uint4*)&sA[row * 32 + sk8] = *(const uint4*)&A[(long)(m0 + row) * 512 + k0 + sk8];
            *(uint4*)&sB[row * 32 + sk8] = *(const uint4*)&Bt[(long)(n0 + row) * 512 + k0 + sk8];
        }
        __syncthreads();
        half8 af[4], bf[4];
#pragma unroll
        for (int mi = 0; mi < 4; mi++)
            af[mi] = *(half8*)&sA[(wm * 64 + mi * 16 + lrow) * 32 + quad * 8];
#pragma unroll
        for (int ni = 0; ni < 4; ni++)
            bf[ni] = *(half8*)&sB[(wn * 64 + ni * 16 + lrow) * 32 + quad * 8];
#pragma unroll
        for (int mi = 0; mi < 4; mi++)
#pragma unroll
            for (int ni = 0; ni < 4; ni++)
                acc[mi][ni] = __builtin_amdgcn_mfma_f32_16x16x32_f16(af[mi], bf[ni], acc[mi][ni], 0, 0, 0);
        __syncthreads();
    }
#pragma unroll
    for (int mi = 0; mi < 4; mi++)
#pragma unroll
        for (int ni = 0; ni < 4; ni++)
#pragma unroll
            for (int r = 0; r < 4; r++) {
                int m = m0 + wm * 64 + mi * 16 + quad * 4 + r;   // m = t*B + b
                int n = n0 + wn * 64 + ni * 16 + lrow;
                float v = acc[mi][ni][r] + bias[n];
                v = fmaxf(v, 0.f);
                int t = m >> 5, b = m & 31;
                out[(long)b * (T_ * (long)N_) + (long)t * N_ + n] = v;
            }
}

// ---------------- phase 2: the recurrence ----------------
// 32 groups (batch) x 8 slice-blocks x 512 threads. Lane map: within wave w,
// lane = g*16 + eoff*2 + hh covers gate g, element e=w*8+eoff, row-half hh of
// column gcol=g*512+s*64+w*8+eoff. All reduce/gate/pack work is wave-local
// shuffles -> ONE barrier per step. h exchange: tagged u64 slots
// ((t+1)<<32 | f16x2) through the device coherence point (sc1) -- the
// R3-proven protocol. 128 pollers read 2 slots each via dwordx4 sc1.
// Double-buffer safety: producer overwrites parity slot (tag t+3 over t+1)
// only after observing tag t+2 on all slices, which transitively requires
// every block's threads to have finished polling tag t+1.
__launch_bounds__(512, 2)
__global__ void lstm_rec(const f16* __restrict__ Ut,      // [2048 cols][512 rows] f16
                         const f16* __restrict__ xpre,    // [B][T][2048] f16
                         u64* __restrict__ hgS,           // [2][32][256] tagged h pairs (LLC)
                         unsigned* __restrict__ hs32)     // [T][B][256] u32 (packed f16x2)
{
    const int tid = threadIdx.x;
    const int bb = blockIdx.x & 31;   // batch
    const int s  = blockIdx.x >> 5;   // slice 0..7
    const int w  = tid >> 6;          // wave 0..7
    const int l  = tid & 63;
    const int g    = l >> 4;          // gate 0..3
    const int eoff = (l >> 1) & 7;    // element within wave's 8
    const int hh   = l & 1;           // row-half
    const int gcol = g * 512 + s * 64 + w * 8 + eoff;   // global gate-column

    // padded double-buffered h (parity): half A words 0..127, half B at 132..259
    __shared__ __align__(16) unsigned hbuf[2][264];

    // U half-column in registers (statically indexed)
    uint4 u[32];
    const uint4* Ub = (const uint4*)(Ut + (long)gcol * 512) + hh * 32;
#pragma unroll
    for (int k = 0; k < 32; k++) u[k] = Ub[k];

    if (tid < 264) hbuf[0][tid] = 0u;   // h_{-1} = 0
    float cst = 0.f;                    // c-state for element w*8+eoff (redundant across g,hh)

    const f16* xp_base = xpre + (long)bb * T_ * NG + gcol;
    float xpv = (hh == 0) ? (float)xp_base[0] : 0.f;   // prologue prefetch (hot by t=0 use)

    const size_t exbase = (size_t)bb * 256;
    const int poller = (tid < 128) && ((tid >> 4) != s);   // own-slice arrives via LDS

    for (int t = 0; t < T_; ++t) {
        // ---- acquire h_{t-1}: poll tagged slot pairs at device scope ----
        if (t > 0 && poller) {
            const u64* slot = hgS + (size_t)(t & 1) * 8192 + exbase + 2 * tid;
            const unsigned tag = (unsigned)t;
            uint4v v;
            for (;;) {
                v = load_2slots_sc1(slot);
                if (v.y == tag && v.w == tag) break;
            }
            const int j = 2 * tid + ((tid >> 6) << 2);   // +4 pad past word 128
            *(uint2*)&hbuf[t & 1][j] = make_uint2(v.x, v.z);
        }

        // prefetch next step's xpre AFTER the poll (hidden across a full step)
        float xpv_next = 0.f;
        if (hh == 0) {
            int tn = (t + 1 < T_) ? t + 1 : t;
            xpv_next = (float)xp_base[(long)tn * NG];
        }
        __syncthreads();

        // ---- dot over this half-column (conflict-free padded broadcast reads) ----
        const uint4* hb = ((const uint4*)hbuf[t & 1]) + (hh ? 33 : 0);
        float a0 = 0.f, a1 = 0.f, a2 = 0.f, a3 = 0.f;
#pragma unroll
        for (int k = 0; k < 32; k++) {
            uint4 hv = hb[k];
            a0 = fdot2(hv.x, u[k].x, a0);
            a1 = fdot2(hv.y, u[k].y, a1);
            a2 = fdot2(hv.z, u[k].z, a2);
            a3 = fdot2(hv.w, u[k].w, a3);
        }
        float sum = (a0 + a1) + (a2 + a3);
        if (hh == 0) sum += xpv;
        float tot = sum + __shfl_xor(sum, 1);      // both halves -> full preactivation

        // gather the 4 gate preactivations for my element (wave-local shuffles)
        const int base = l & 15;
        float pi = __shfl(tot, base);
        float pf = __shfl(tot, base + 16);
        float pg = __shfl(tot, base + 32);
        float pc = __shfl(tot, base + 48);

        float gi = sigmoid_fast(pi);
        float gf = sigmoid_fast(pf);
        float gg = sigmoid_fast(pg);
        float ct = tanh_fast(pc);
        cst = gf * cst + gi * ct;
        float h = gg * tanh_fast(cst);

        // pack element pairs: even-eoff lanes take neighbor's h
        float ho = __shfl_xor(h, 2);
        if ((l & 3) == 0 && g == 0) {              // lanes 0,4,8,12: eoff even, hh=0, gate 0
            union { f16 hx[2]; unsigned u; } pk;
            pk.hx[0] = (f16)h;  pk.hx[1] = (f16)ho;
            const int j = s * 32 + w * 4 + (l >> 2);          // global h-word index
            const u64 pv = ((u64)(unsigned)(t + 1) << 32) | (u64)pk.u;
            __hip_atomic_store(hgS + (size_t)((t + 1) & 1) * 8192 + exbase + j, pv,
                               __ATOMIC_RELAXED, __HIP_MEMORY_SCOPE_AGENT);
            hs32[((long)t * B_ + bb) * 256 + j] = pk.u;        // history for gemm_hw
            hbuf[(t + 1) & 1][j + ((j >> 7) << 2)] = pk.u;     // own slice direct to LDS
        }
        xpv = xpv_next;
        // single barrier per step: next iteration's __syncthreads orders hbuf
    }
}

// ---------------- launch ----------------
extern "C" void kernel_launch(void* const* d_in, const int* in_sizes, int n_in,
                              void* d_out, int out_size, void* d_ws, size_t ws_size,
                              hipStream_t stream)
{
    const float* x  = (const float*)d_in[0];
    const float* Wi = (const float*)d_in[1];
    const float* Ui = (const float*)d_in[2];
    const float* Wf = (const float*)d_in[3];
    const float* Uf = (const float*)d_in[4];
    const float* Wg = (const float*)d_in[5];
    const float* Ug = (const float*)d_in[6];
    const float* Wc = (const float*)d_in[7];
    const float* Uc = (const float*)d_in[8];
    const float* Wo = (const float*)d_in[9];
    const float* bi = (const float*)d_in[10];
    const float* bf = (const float*)d_in[11];
    const float* bg = (const float*)d_in[12];
    const float* bc = (const float*)d_in[13];
    const float* bo = (const float*)d_in[14];

    char* ws = (char*)d_ws;
    f16*      x16   = (f16*)(ws + 0L);            // 64 MB
    f16*      xpre  = (f16*)(ws + 67108864L);     // 256 MB
    f16*      hs    = (f16*)(ws + 335544320L);    // 64 MB
    f16*      wt    = (f16*)(ws + 402653184L);    // 2 MB
    f16*      ut    = (f16*)(ws + 404750336L);    // 2 MB
    f16*      wot   = (f16*)(ws + 406847488L);    // 0.5 MB
    float*    bias  = (float*)(ws + 407371776L);  // 8 KB
    u64*      hgS   = (u64*)(ws + 407379968L);    // 128 KB tagged h exchange
    // hgS is re-poisoned to 0xAA each call -> tag 0xAAAAAAAA never matches a
    // real t in [1,2048], so stale data cannot satisfy a poll.

    prep_cast<<<dim3(32768), dim3(256), 0, stream>>>(x, x16);
    prep_w<<<dim3(1024, 10), dim3(256), 0, stream>>>(Wi, Ui, Wf, Uf, Wg, Ug, Wc, Uc, Wo,
                                                     bi, bf, bg, bc, wt, ut, wot, bias);
    gemm_xw<<<dim3(16, 512), dim3(256), 0, stream>>>(x16, wt, bias, xpre);
    lstm_rec<<<dim3(256), dim3(512), 0, stream>>>(ut, xpre, hgS, (unsigned*)hs);
    gemm_hw<<<dim3(4, 512), dim3(256), 0, stream>>>(hs, wot, bo, (float*)d_out);
}

// Round 6
// 5606.989 us; speedup vs baseline: 1.2034x; 1.0031x over previous
//
#include <hip/hip_runtime.h>
#include <stdint.h>

// Problem constants
#define B_ 32
#define T_ 2048
#define D_ 512
#define N_ 512
#define NG 2048   // 4 gates * N

typedef _Float16 f16;
typedef _Float16 half2v __attribute__((ext_vector_type(2)));
typedef _Float16 half8  __attribute__((ext_vector_type(8)));
typedef float    float4v __attribute__((ext_vector_type(4)));
typedef unsigned uint4v  __attribute__((ext_vector_type(4)));
typedef unsigned long long u64;

union U32H2 { unsigned u; half2v h; };

static __device__ __forceinline__ float fdot2(unsigned a, unsigned b, float c) {
#if __has_builtin(__builtin_amdgcn_fdot2)
    U32H2 ua; ua.u = a; U32H2 ub; ub.u = b;
    return __builtin_amdgcn_fdot2(ua.h, ub.h, c, false);
#else
    U32H2 ua; ua.u = a; U32H2 ub; ub.u = b;
    c += (float)ua.h[0] * (float)ub.h[0];
    c += (float)ua.h[1] * (float)ub.h[1];
    return c;
#endif
}

// device-scope (sc1) 16B load of two tagged u64 slots; own waitcnt.
static __device__ __forceinline__ uint4v load_2slots_sc1(const u64* p) {
    uint4v v;
    asm volatile("global_load_dwordx4 %0, %1, off sc1\n\ts_waitcnt vmcnt(0)"
                 : "=v"(v) : "v"(p) : "memory");
    return v;
}

static __device__ __forceinline__ float sigmoid_fast(float x) {
    return 1.f / (1.f + __expf(-x));
}
static __device__ __forceinline__ float tanh_fast(float x) {
    x = fminf(fmaxf(x, -15.f), 15.f);   // tanh saturates to +-1 well before 15
    float e = __expf(2.f * x);
    return (e - 1.f) / (e + 1.f);
}

// ---------------- prep: cast x (f32) -> f16 ----------------
__global__ void prep_cast(const float* __restrict__ x, f16* __restrict__ x16) {
    long i = ((long)blockIdx.x * 256 + threadIdx.x) * 4;
    float4 v = *(const float4*)(x + i);
    union { f16 h[4]; uint2 u; } pk;
    pk.h[0] = (f16)v.x; pk.h[1] = (f16)v.y; pk.h[2] = (f16)v.z; pk.h[3] = (f16)v.w;
    *(uint2*)(x16 + i) = pk.u;
}

// ---------------- prep: transpose+cast weights, biases ----------------
__global__ void prep_w(const float* __restrict__ Wi, const float* __restrict__ Ui,
                       const float* __restrict__ Wf, const float* __restrict__ Uf,
                       const float* __restrict__ Wg, const float* __restrict__ Ug,
                       const float* __restrict__ Wc, const float* __restrict__ Uc,
                       const float* __restrict__ Wo,
                       const float* __restrict__ bi, const float* __restrict__ bff,
                       const float* __restrict__ bg, const float* __restrict__ bc,
                       f16* __restrict__ wt, f16* __restrict__ ut,
                       f16* __restrict__ wot, float* __restrict__ bias)
{
    const int y = blockIdx.y;
    const int e = blockIdx.x * 256 + threadIdx.x;   // 0..262143
    if (y < 4) {
        const float* src = (y == 0) ? Wi : (y == 1) ? Wf : (y == 2) ? Wg : Wc;
        int col = e >> 9, d = e & 511;
        wt[(long)y * 512 * 512 + e] = (f16)src[(long)d * 512 + col];   // wt[(g*512+col)][d]
    } else if (y < 8) {
        const float* src = (y == 4) ? Ui : (y == 5) ? Uf : (y == 6) ? Ug : Uc;
        int col = e >> 9, d = e & 511;
        ut[(long)(y - 4) * 512 * 512 + e] = (f16)src[(long)d * 512 + col];
    } else if (y == 8) {
        int col = e >> 9, d = e & 511;
        wot[e] = (f16)Wo[(long)d * 512 + col];
    } else {
        if (e < 2048) {
            const float* bsrc = (e < 512) ? bi : (e < 1024) ? bff : (e < 1536) ? bg : bc;
            bias[e] = bsrc[e & 511];
        }
    }
}

// ---------------- phase 1: xpre[b][t][2048] = x @ [Wi|Wf|Wg|Wc] + bias (f16 out) ----------------
__launch_bounds__(256)
__global__ void gemm_xw(const f16* __restrict__ A, const f16* __restrict__ Bt,
                        const float* __restrict__ bias, f16* __restrict__ C)
{
    __shared__ f16 sA[128 * 32];
    __shared__ f16 sB[128 * 32];
    const int tid = threadIdx.x;
    const int m0 = blockIdx.y * 128;
    const int n0 = blockIdx.x * 128;
    const int wave = tid >> 6, lane = tid & 63;
    const int wm = wave >> 1, wn = wave & 1;
    const int lrow = lane & 15, quad = lane >> 4;

    float4v acc[4][4];
#pragma unroll
    for (int i = 0; i < 4; i++)
#pragma unroll
        for (int j = 0; j < 4; j++) acc[i][j] = (float4v){0.f, 0.f, 0.f, 0.f};

    const int srow = tid >> 2;        // 0..63
    const int sk8 = (tid & 3) * 8;    // 0,8,16,24

    for (int k0 = 0; k0 < 512; k0 += 32) {
#pragma unroll
        for (int rr = 0; rr < 128; rr += 64) {
            const int row = rr + srow;
            *(uint4*)&sA[row * 32 + sk8] = *(const uint4*)&A[(long)(m0 + row) * 512 + k0 + sk8];
            *(uint4*)&sB[row * 32 + sk8] = *(const uint4*)&Bt[(long)(n0 + row) * 512 + k0 + sk8];
        }
        __syncthreads();
        half8 af[4], bf[4];
#pragma unroll
        for (int mi = 0; mi < 4; mi++)
            af[mi] = *(half8*)&sA[(wm * 64 + mi * 16 + lrow) * 32 + quad * 8];
#pragma unroll
        for (int ni = 0; ni < 4; ni++)
            bf[ni] = *(half8*)&sB[(wn * 64 + ni * 16 + lrow) * 32 + quad * 8];
#pragma unroll
        for (int mi = 0; mi < 4; mi++)
#pragma unroll
            for (int ni = 0; ni < 4; ni++)
                acc[mi][ni] = __builtin_amdgcn_mfma_f32_16x16x32_f16(af[mi], bf[ni], acc[mi][ni], 0, 0, 0);
        __syncthreads();
    }
#pragma unroll
    for (int mi = 0; mi < 4; mi++)
#pragma unroll
        for (int ni = 0; ni < 4; ni++)
#pragma unroll
            for (int r = 0; r < 4; r++) {
                int m = m0 + wm * 64 + mi * 16 + quad * 4 + r;
                int n = n0 + wn * 64 + ni * 16 + lrow;
                C[(long)m * NG + n] = (f16)(acc[mi][ni][r] + bias[n]);
            }
}

// ---------------- phase 3: out[b][t][n] = relu(hs @ Wo + bo) (f32 out, row remap) ----------------
__launch_bounds__(256)
__global__ void gemm_hw(const f16* __restrict__ A, const f16* __restrict__ Bt,
                        const float* __restrict__ bias, float* __restrict__ out)
{
    __shared__ f16 sA[128 * 32];
    __shared__ f16 sB[128 * 32];
    const int tid = threadIdx.x;
    const int m0 = blockIdx.y * 128;
    const int n0 = blockIdx.x * 128;
    const int wave = tid >> 6, lane = tid & 63;
    const int wm = wave >> 1, wn = wave & 1;
    const int lrow = lane & 15, quad = lane >> 4;

    float4v acc[4][4];
#pragma unroll
    for (int i = 0; i < 4; i++)
#pragma unroll
        for (int j = 0; j < 4; j++) acc[i][j] = (float4v){0.f, 0.f, 0.f, 0.f};

    const int srow = tid >> 2;
    const int sk8 = (tid & 3) * 8;

    for (int k0 = 0; k0 < 512; k0 += 32) {
#pragma unroll
        for (int rr = 0; rr < 128; rr += 64) {
            const int row = rr + srow;
            *(uint4*)&sA[row * 32 + sk8] = *(const uint4*)&A[(long)(m0 + row) * 512 + k0 + sk8];
            *(uint4*)&sB[row * 32 + sk8] = *(const uint4*)&Bt[(long)(n0 + row) * 512 + k0 + sk8];
        }
        __syncthreads();
        half8 af[4], bf[4];
#pragma unroll
        for (int mi = 0; mi < 4; mi++)
            af[mi] = *(half8*)&sA[(wm * 64 + mi * 16 + lrow) * 32 + quad * 8];
#pragma unroll
        for (int ni = 0; ni < 4; ni++)
            bf[ni] = *(half8*)&sB[(wn * 64 + ni * 16 + lrow) * 32 + quad * 8];
#pragma unroll
        for (int mi = 0; mi < 4; mi++)
#pragma unroll
            for (int ni = 0; ni < 4; ni++)
                acc[mi][ni] = __builtin_amdgcn_mfma_f32_16x16x32_f16(af[mi], bf[ni], acc[mi][ni], 0, 0, 0);
        __syncthreads();
    }
#pragma unroll
    for (int mi = 0; mi < 4; mi++)
#pragma unroll
        for (int ni = 0; ni < 4; ni++)
#pragma unroll
            for (int r = 0; r < 4; r++) {
                int m = m0 + wm * 64 + mi * 16 + quad * 4 + r;   // m = t*B + b
                int n = n0 + wn * 64 + ni * 16 + lrow;
                float v = acc[mi][ni][r] + bias[n];
                v = fmaxf(v, 0.f);
                int t = m >> 5, b = m & 31;
                out[(long)b * (T_ * (long)N_) + (long)t * N_ + n] = v;
            }
}

// ---------------- phase 2: the recurrence ----------------
// 32 groups (batch) x 8 slice-blocks x 512 threads. Lane map: within wave w,
// lane = g*16 + eoff*2 + hh covers gate g, element e=w*8+eoff, row-half hh of
// column gcol=g*512+s*64+w*8+eoff. All reduce/gate/pack work is wave-local
// shuffles -> ONE barrier per step. h exchange: tagged u64 slots
// ((t+1)<<32 | f16x2) at device scope (sc1) -- the R3-proven protocol.
//
// R6 fix: U is PINNED in VGPRs via an asm value-barrier after the load loop.
// R5's VGPR_Count=84 proved the compiler was re-loading u[] from L2 every
// step (~26 TB/s of L2 traffic -- the real bottleneck). The asm makes the
// loaded values opaque, so they must stay live in registers (128 VGPRs for U).
__launch_bounds__(512, 2)
__global__ void lstm_rec(const f16* __restrict__ Ut,      // [2048 cols][512 rows] f16
                         const f16* __restrict__ xpre,    // [B][T][2048] f16
                         u64* __restrict__ hgS,           // [2][32][256] tagged h pairs (LLC)
                         unsigned* __restrict__ hs32)     // [T][B][256] u32 (packed f16x2)
{
    const int tid = threadIdx.x;
    const int bb = blockIdx.x & 31;   // batch
    const int s  = blockIdx.x >> 5;   // slice 0..7
    const int w  = tid >> 6;          // wave 0..7
    const int l  = tid & 63;
    const int g    = l >> 4;          // gate 0..3
    const int eoff = (l >> 1) & 7;    // element within wave's 8
    const int hh   = l & 1;           // row-half
    const int gcol = g * 512 + s * 64 + w * 8 + eoff;   // global gate-column

    // padded double-buffered h (parity): half A words 0..127, half B at 132..259
    __shared__ __align__(16) unsigned hbuf[2][264];

    // U half-column: load once, then PIN in VGPRs (opaque to the optimizer)
    uint4 u[32];
    const uint4* Ub = (const uint4*)(Ut + (long)gcol * 512) + hh * 32;
#pragma unroll
    for (int k = 0; k < 32; k++) u[k] = Ub[k];
#pragma unroll
    for (int k = 0; k < 32; k++)
        asm volatile("" : "+v"(u[k].x), "+v"(u[k].y), "+v"(u[k].z), "+v"(u[k].w));

    if (tid < 264) hbuf[0][tid] = 0u;   // h_{-1} = 0
    float cst = 0.f;                    // c-state for element w*8+eoff (redundant across g,hh)

    const f16* xp_base = xpre + (long)bb * T_ * NG + gcol;
    float xpv = (hh == 0) ? (float)xp_base[0] : 0.f;   // prologue prefetch (hot by t=0 use)

    const size_t exbase = (size_t)bb * 256;
    const int poller = (tid < 128) && ((tid >> 4) != s);   // own-slice arrives via LDS

    for (int t = 0; t < T_; ++t) {
        // ---- acquire h_{t-1}: poll tagged slot pairs at device scope ----
        if (t > 0 && poller) {
            const u64* slot = hgS + (size_t)(t & 1) * 8192 + exbase + 2 * tid;
            const unsigned tag = (unsigned)t;
            uint4v v;
            for (;;) {
                v = load_2slots_sc1(slot);
                if (v.y == tag && v.w == tag) break;
            }
            const int j = 2 * tid + ((tid >> 6) << 2);   // +4 pad past word 128
            *(uint2*)&hbuf[t & 1][j] = make_uint2(v.x, v.z);
        }

        // prefetch next step's xpre AFTER the poll (hidden across a full step)
        float xpv_next = 0.f;
        if (hh == 0) {
            int tn = (t + 1 < T_) ? t + 1 : t;
            xpv_next = (float)xp_base[(long)tn * NG];
        }
        __syncthreads();

        // ---- dot over this half-column (conflict-free padded broadcast reads) ----
        const uint4* hb = ((const uint4*)hbuf[t & 1]) + (hh ? 33 : 0);
        float a0 = 0.f, a1 = 0.f, a2 = 0.f, a3 = 0.f;
#pragma unroll
        for (int k = 0; k < 32; k++) {
            uint4 hv = hb[k];
            a0 = fdot2(hv.x, u[k].x, a0);
            a1 = fdot2(hv.y, u[k].y, a1);
            a2 = fdot2(hv.z, u[k].z, a2);
            a3 = fdot2(hv.w, u[k].w, a3);
        }
        float sum = (a0 + a1) + (a2 + a3);
        if (hh == 0) sum += xpv;
        float tot = sum + __shfl_xor(sum, 1);      // both halves -> full preactivation

        // gather the 4 gate preactivations for my element (wave-local shuffles)
        const int base = l & 15;
        float pi = __shfl(tot, base);
        float pf = __shfl(tot, base + 16);
        float pg = __shfl(tot, base + 32);
        float pc = __shfl(tot, base + 48);

        float gi = sigmoid_fast(pi);
        float gf = sigmoid_fast(pf);
        float gg = sigmoid_fast(pg);
        float ct = tanh_fast(pc);
        cst = gf * cst + gi * ct;
        float h = gg * tanh_fast(cst);

        // pack element pairs: even-eoff lanes take neighbor's h
        float ho = __shfl_xor(h, 2);
        if ((l & 3) == 0 && g == 0) {              // lanes 0,4,8,12: eoff even, hh=0, gate 0
            union { f16 hx[2]; unsigned u; } pk;
            pk.hx[0] = (f16)h;  pk.hx[1] = (f16)ho;
            const int j = s * 32 + w * 4 + (l >> 2);          // global h-word index
            const u64 pv = ((u64)(unsigned)(t + 1) << 32) | (u64)pk.u;
            __hip_atomic_store(hgS + (size_t)((t + 1) & 1) * 8192 + exbase + j, pv,
                               __ATOMIC_RELAXED, __HIP_MEMORY_SCOPE_AGENT);
            hs32[((long)t * B_ + bb) * 256 + j] = pk.u;        // history for gemm_hw
            hbuf[(t + 1) & 1][j + ((j >> 7) << 2)] = pk.u;     // own slice direct to LDS
        }
        xpv = xpv_next;
        // single barrier per step: next iteration's __syncthreads orders hbuf
    }
}

// ---------------- launch ----------------
extern "C" void kernel_launch(void* const* d_in, const int* in_sizes, int n_in,
                              void* d_out, int out_size, void* d_ws, size_t ws_size,
                              hipStream_t stream)
{
    const float* x  = (const float*)d_in[0];
    const float* Wi = (const float*)d_in[1];
    const float* Ui = (const float*)d_in[2];
    const float* Wf = (const float*)d_in[3];
    const float* Uf = (const float*)d_in[4];
    const float* Wg = (const float*)d_in[5];
    const float* Ug = (const float*)d_in[6];
    const float* Wc = (const float*)d_in[7];
    const float* Uc = (const float*)d_in[8];
    const float* Wo = (const float*)d_in[9];
    const float* bi = (const float*)d_in[10];
    const float* bf = (const float*)d_in[11];
    const float* bg = (const float*)d_in[12];
    const float* bc = (const float*)d_in[13];
    const float* bo = (const float*)d_in[14];

    char* ws = (char*)d_ws;
    f16*      x16   = (f16*)(ws + 0L);            // 64 MB
    f16*      xpre  = (f16*)(ws + 67108864L);     // 256 MB
    f16*      hs    = (f16*)(ws + 335544320L);    // 64 MB
    f16*      wt    = (f16*)(ws + 402653184L);    // 2 MB
    f16*      ut    = (f16*)(ws + 404750336L);    // 2 MB
    f16*      wot   = (f16*)(ws + 406847488L);    // 0.5 MB
    float*    bias  = (float*)(ws + 407371776L);  // 8 KB
    u64*      hgS   = (u64*)(ws + 407379968L);    // 128 KB tagged h exchange
    // hgS is re-poisoned to 0xAA each call -> tag 0xAAAAAAAA never matches a
    // real t in [1,2048], so stale data cannot satisfy a poll.

    prep_cast<<<dim3(32768), dim3(256), 0, stream>>>(x, x16);
    prep_w<<<dim3(1024, 10), dim3(256), 0, stream>>>(Wi, Ui, Wf, Uf, Wg, Ug, Wc, Uc, Wo,
                                                     bi, bf, bg, bc, wt, ut, wot, bias);
    gemm_xw<<<dim3(16, 512), dim3(256), 0, stream>>>(x16, wt, bias, xpre);
    lstm_rec<<<dim3(256), dim3(512), 0, stream>>>(ut, xpre, hgS, (unsigned*)hs);
    gemm_hw<<<dim3(4, 512), dim3(256), 0, stream>>>(hs, wot, bo, (float*)d_out);
}